// Round 11
// baseline (272.768 us; speedup 1.0000x reference)
//
#include <hip/hip_runtime.h>
#include <hip/hip_bf16.h>

// GCN 2-layer, N=100000, E=1.6M, 64->64(relu)->32.
// out[d] = dis[d]*(sum_{s in N(d)} dis[s]*h[s] + dis[d]*h[d]) + b  (per layer).
// Pipeline: edge pass (single atomic pass -> 64-slot dst buckets) ->
// gemm1 (outer-product, dis folded into epilogue) -> agg1 -> gemm2 (dis folded)
// -> agg2. Feature rows bf16; f32 accumulation everywhere.

constexpr int N = 100000;
constexpr int E = 1600000;
constexpr int EBK = (E + 1023) / 1024;  // 1563 edge blocks
constexpr int GB  = (N + 63) / 64;      // 1563 gemm1 blocks

// ---- edge pass: histogram + direct bucket placement, 4 chains/thread ----
__global__ void edge_kernel(const int* __restrict__ src, const int* __restrict__ dst,
                            int* __restrict__ cnt, unsigned* __restrict__ pedge) {
    const int base = blockIdx.x * 1024 + threadIdx.x;
    int d[4], s[4];
    bool ok[4];
#pragma unroll
    for (int u = 0; u < 4; ++u) {
        int idx = base + u * 256;
        ok[u] = idx < E;
        d[u] = ok[u] ? dst[idx] : 0;
        s[u] = ok[u] ? src[idx] : 0;
    }
    int r[4];
#pragma unroll
    for (int u = 0; u < 4; ++u)
        r[u] = ok[u] ? atomicAdd(&cnt[d[u]], 1) : 64;
#pragma unroll
    for (int u = 0; u < 4; ++u)
        if (r[u] < 64) pedge[(d[u] << 6) + r[u]] = (unsigned)s[u];
}

// ---- gemm1: h1[n] = (x @ W1)[n] * dis[n] -> bf16. 64-row outer-product. ----
__global__ void __launch_bounds__(256) gemm1_kernel(
    const float* __restrict__ x, const float* __restrict__ W1,
    const int* __restrict__ cnt, __hip_bfloat16* __restrict__ h1) {
    __shared__ float ws[64][64];    // W1 [k][c]
    __shared__ float xsT[64][64];   // x tile transposed [k][r]
    const int row0 = blockIdx.x * 64;
    const int t = threadIdx.x;
    for (int i = t * 4; i < 64 * 64; i += 1024) {
        float4 v = *(const float4*)(W1 + i);
        ws[i >> 6][i & 63]       = v.x;
        ws[i >> 6][(i & 63) + 1] = v.y;
        ws[i >> 6][(i & 63) + 2] = v.z;
        ws[i >> 6][(i & 63) + 3] = v.w;
    }
    {
        const int r  = t & 63;
        const int k0 = (t >> 6) * 16;
        const int gr = row0 + r;
        if (gr < N) {
#pragma unroll
            for (int kk = 0; kk < 16; kk += 4) {
                float4 v = *(const float4*)(x + (size_t)gr * 64 + k0 + kk);
                xsT[k0 + kk][r]     = v.x;
                xsT[k0 + kk + 1][r] = v.y;
                xsT[k0 + kk + 2][r] = v.z;
                xsT[k0 + kk + 3][r] = v.w;
            }
        } else {
#pragma unroll
            for (int kk = 0; kk < 16; ++kk) xsT[k0 + kk][r] = 0.0f;
        }
    }
    __syncthreads();
    const int c4 = (t & 15) * 4;
    const int r4 = (t >> 4) * 4;
    float acc[4][4];
#pragma unroll
    for (int i = 0; i < 4; ++i)
#pragma unroll
        for (int j = 0; j < 4; ++j) acc[i][j] = 0.0f;
#pragma unroll 4
    for (int k = 0; k < 64; ++k) {
        float4 wv = *(const float4*)&ws[k][c4];
        float4 xv = *(const float4*)&xsT[k][r4];
        float xa[4] = {xv.x, xv.y, xv.z, xv.w};
        float wa[4] = {wv.x, wv.y, wv.z, wv.w};
#pragma unroll
        for (int i = 0; i < 4; ++i)
#pragma unroll
            for (int j = 0; j < 4; ++j) acc[i][j] += xa[i] * wa[j];
    }
#pragma unroll
    for (int i = 0; i < 4; ++i) {
        const int gr = row0 + r4 + i;
        if (gr < N) {
            float dn = rsqrtf((float)cnt[gr] + 1.0f);
            unsigned short o[4];
#pragma unroll
            for (int j = 0; j < 4; ++j)
                o[j] = __bfloat16_as_ushort(__float2bfloat16(acc[i][j] * dn));
            *(ushort4*)((unsigned short*)h1 + (size_t)gr * 64 + c4) =
                *(const ushort4*)o;
        }
    }
}

__device__ __forceinline__ void bf8_acc(float* acc, uint4 r) {
    const unsigned u[4] = {r.x, r.y, r.z, r.w};
#pragma unroll
    for (int k = 0; k < 4; ++k) {
        acc[2 * k]     += __uint_as_float(u[k] << 16);
        acc[2 * k + 1] += __uint_as_float(u[k] & 0xffff0000u);
    }
}

// ---- layer-1 agg: wave/node, 8 slots x 8 lanes x 8 bf16 feats, unroll x2.
// h pre-scaled by dis[src]. out = relu(dis[n]*(sum + h[n]) + b) -> bf16.
__global__ void agg1_kernel(const __hip_bfloat16* __restrict__ h,
                            const unsigned* __restrict__ pedge, const int* __restrict__ cnt,
                            const float* __restrict__ b, __hip_bfloat16* __restrict__ z) {
    const int n = (blockIdx.x * blockDim.x + threadIdx.x) >> 6;
    const int lane = threadIdx.x & 63;
    const int c = cnt[n];
    const int deg = (c < 64) ? c : 64;
    const int q  = lane >> 3;
    const int fq = (lane & 7) * 8;
    const int base = n << 6;
    const unsigned short* hp = (const unsigned short*)h;
    float acc[8];
#pragma unroll
    for (int i = 0; i < 8; ++i) acc[i] = 0.0f;
    for (int j = q; j < deg; j += 16) {
        int s0 = (int)pedge[base + j];
        uint4 r0 = *(const uint4*)(hp + (size_t)s0 * 64 + fq);
        int j2 = j + 8;
        if (j2 < deg) {
            int s1 = (int)pedge[base + j2];
            uint4 r1 = *(const uint4*)(hp + (size_t)s1 * 64 + fq);
            bf8_acc(acc, r0);
            bf8_acc(acc, r1);
        } else {
            bf8_acc(acc, r0);
        }
    }
#pragma unroll
    for (int i = 0; i < 8; ++i) {
        acc[i] += __shfl_xor(acc[i], 8);
        acc[i] += __shfl_xor(acc[i], 16);
        acc[i] += __shfl_xor(acc[i], 32);
    }
    if (q == 0) {
        float dn = rsqrtf((float)c + 1.0f);
        uint4 sr = *(const uint4*)(hp + (size_t)n * 64 + fq);
        bf8_acc(acc, sr);  // self term (already dis-scaled)
        float4 b0 = *(const float4*)(b + fq);
        float4 b1 = *(const float4*)(b + fq + 4);
        float bb[8] = {b0.x, b0.y, b0.z, b0.w, b1.x, b1.y, b1.z, b1.w};
        unsigned short o[8];
#pragma unroll
        for (int i = 0; i < 8; ++i) {
            float v = fmaxf(dn * acc[i] + bb[i], 0.0f);
            o[i] = __bfloat16_as_ushort(__float2bfloat16(v));
        }
        *(uint4*)((unsigned short*)z + (size_t)n * 64 + fq) = *(const uint4*)o;
    }
}

// ---- gemm2: h2s[n] = (z1 @ W2)[n] * dis[n] -> bf16 (dis folded) ----
__global__ void __launch_bounds__(256) gemm2_kernel(
    const __hip_bfloat16* __restrict__ Z, const float* __restrict__ W2,
    const int* __restrict__ cnt, __hip_bfloat16* __restrict__ H2) {
    __shared__ float ws[64][32];
    __shared__ float xs[32][64];
    const int t = threadIdx.x;
    for (int i = t; i < 64 * 32; i += 256) ws[i >> 5][i & 31] = W2[i];
    const int row0 = blockIdx.x * 32;
    const unsigned short* Zp = (const unsigned short*)Z;
#pragma unroll
    for (int h = 0; h < 2; ++h) {
        int idx = h * 1024 + t * 4;
        int r = idx >> 6, k = idx & 63;
        ushort4 v = *(const ushort4*)(Zp + (size_t)(row0 + r) * 64 + k);
        xs[r][k]     = __uint_as_float((unsigned)v.x << 16);
        xs[r][k + 1] = __uint_as_float((unsigned)v.y << 16);
        xs[r][k + 2] = __uint_as_float((unsigned)v.z << 16);
        xs[r][k + 3] = __uint_as_float((unsigned)v.w << 16);
    }
    __syncthreads();
    const int c  = t & 31;
    const int rb = (t >> 5) * 4;
    float acc[4] = {0.f, 0.f, 0.f, 0.f};
    for (int k0 = 0; k0 < 64; k0 += 4) {
        float w0 = ws[k0][c], w1 = ws[k0 + 1][c];
        float w2 = ws[k0 + 2][c], w3 = ws[k0 + 3][c];
#pragma unroll
        for (int i = 0; i < 4; ++i) {
            float4 xv = *(const float4*)&xs[rb + i][k0];
            acc[i] += xv.x * w0;
            acc[i] += xv.y * w1;
            acc[i] += xv.z * w2;
            acc[i] += xv.w * w3;
        }
    }
#pragma unroll
    for (int i = 0; i < 4; ++i) {
        int row = row0 + rb + i;
        float dn = rsqrtf((float)cnt[row] + 1.0f);
        H2[(size_t)row * 32 + c] = __float2bfloat16(acc[i] * dn);
    }
}

// ---- layer-2 agg: wave/node, 16 slots x 4 lanes x 8 bf16 feats, unroll x2.
// h pre-scaled. out = dis[n]*(sum + h[n]) + b -> f32. ----
__global__ void agg2_kernel(const __hip_bfloat16* __restrict__ h,
                            const unsigned* __restrict__ pedge, const int* __restrict__ cnt,
                            const float* __restrict__ b, float* __restrict__ out) {
    const int n = (blockIdx.x * blockDim.x + threadIdx.x) >> 6;
    const int lane = threadIdx.x & 63;
    const int c = cnt[n];
    const int deg = (c < 64) ? c : 64;
    const int q  = lane >> 2;
    const int fq = (lane & 3) * 8;
    const int base = n << 6;
    const unsigned short* hp = (const unsigned short*)h;
    float acc[8];
#pragma unroll
    for (int i = 0; i < 8; ++i) acc[i] = 0.0f;
    for (int j = q; j < deg; j += 32) {
        int s0 = (int)pedge[base + j];
        uint4 r0 = *(const uint4*)(hp + (size_t)s0 * 32 + fq);
        int j2 = j + 16;
        if (j2 < deg) {
            int s1 = (int)pedge[base + j2];
            uint4 r1 = *(const uint4*)(hp + (size_t)s1 * 32 + fq);
            bf8_acc(acc, r0);
            bf8_acc(acc, r1);
        } else {
            bf8_acc(acc, r0);
        }
    }
#pragma unroll
    for (int i = 0; i < 8; ++i) {
        acc[i] += __shfl_xor(acc[i], 4);
        acc[i] += __shfl_xor(acc[i], 8);
        acc[i] += __shfl_xor(acc[i], 16);
        acc[i] += __shfl_xor(acc[i], 32);
    }
    if (q == 0) {
        float dn = rsqrtf((float)c + 1.0f);
        uint4 sr = *(const uint4*)(hp + (size_t)n * 32 + fq);
        bf8_acc(acc, sr);  // self term
        float4 b0 = *(const float4*)(b + fq);
        float4 b1 = *(const float4*)(b + fq + 4);
        float bb[8] = {b0.x, b0.y, b0.z, b0.w, b1.x, b1.y, b1.z, b1.w};
        float o[8];
#pragma unroll
        for (int i = 0; i < 8; ++i) o[i] = dn * acc[i] + bb[i];
        *(float4*)(out + (size_t)n * 32 + fq)     = make_float4(o[0], o[1], o[2], o[3]);
        *(float4*)(out + (size_t)n * 32 + fq + 4) = make_float4(o[4], o[5], o[6], o[7]);
    }
}

extern "C" void kernel_launch(void* const* d_in, const int* in_sizes, int n_in,
                              void* d_out, int out_size, void* d_ws, size_t ws_size,
                              hipStream_t stream) {
    const float* x  = (const float*)d_in[0];
    const int*   ei = (const int*)d_in[1];
    const float* W1 = (const float*)d_in[2];
    const float* b1 = (const float*)d_in[3];
    const float* W2 = (const float*)d_in[4];
    const float* b2 = (const float*)d_in[5];
    float* out = (float*)d_out;

    const int* src = ei;
    const int* dst = ei + E;

    constexpr size_t NP = 100352;
    int*      cnt   = (int*)d_ws;                              // NP ints
    unsigned* pedge = (unsigned*)(cnt + NP);                   // N*64 (25.6 MB)
    __hip_bfloat16* h1b = (__hip_bfloat16*)(pedge + (size_t)N * 64);  // N*64
    __hip_bfloat16* z1b = h1b + (size_t)N * 64;                       // N*64
    __hip_bfloat16* h2s = z1b + (size_t)N * 64;                       // N*32

    hipMemsetAsync(cnt, 0, NP * sizeof(int), stream);
    edge_kernel<<<EBK, 256, 0, stream>>>(src, dst, cnt, pedge);
    gemm1_kernel<<<GB, 256, 0, stream>>>(x, W1, cnt, h1b);
    agg1_kernel<<<N / 4, 256, 0, stream>>>(h1b, pedge, cnt, b1, z1b);
    gemm2_kernel<<<N / 32, 256, 0, stream>>>(z1b, W2, cnt, h2s);
    agg2_kernel<<<N / 4, 256, 0, stream>>>(h2s, pedge, cnt, b2, out);
}

// Round 12
// 258.337 us; speedup vs baseline: 1.0559x; 1.0559x over previous
//
#include <hip/hip_runtime.h>
#include <hip/hip_bf16.h>

// GCN 2-layer, N=100000, E=1.6M, 64->64(relu)->32.
// out[d] = dis[d]*(sum_{s in N(d)} dis[s]*h[s] + dis[d]*h[d]) + b  (per layer).
// Single atomic pass builds fixed 64-slot dst buckets (src only), fused 1:1
// with outer-product gemm1 blocks (gemm rides in the atomic latency shadow).
// agg1 applies dis[src] per edge from L2-resident cnt (no scale pass).

constexpr int N = 100000;
constexpr int E = 1600000;
constexpr int GB = 1563;   // gemm1 blocks (64 rows each, covers 100032)
constexpr int EBK = 1563;  // edge blocks (1024 edges each, covers 1600512)

// ---- fused: gemm1 (X f32 @ W1 -> h1 bf16, unscaled) interleaved with
//      single-pass histogram + bucket placement ----
__global__ void __launch_bounds__(256) fused_gemm1_rank_kernel(
    const float* __restrict__ x, const float* __restrict__ W1,
    __hip_bfloat16* __restrict__ h1,
    const int* __restrict__ src, const int* __restrict__ dst,
    int* __restrict__ cnt, unsigned* __restrict__ pedge) {
    __shared__ float ws[64][64];    // 16 KB, W1 [k][c]
    __shared__ float xsT[64][64];   // 16 KB, x tile transposed [k][r]
    const int bid = blockIdx.x;
    if ((bid & 1) == 0) {
        // ---- gemm block: 64 rows, outer-product 4x4 per thread ----
        const int row0 = (bid >> 1) * 64;
        const int t = threadIdx.x;
        for (int i = t * 4; i < 64 * 64; i += 1024) {
            float4 v = *(const float4*)(W1 + i);
            ws[i >> 6][i & 63]       = v.x;
            ws[i >> 6][(i & 63) + 1] = v.y;
            ws[i >> 6][(i & 63) + 2] = v.z;
            ws[i >> 6][(i & 63) + 3] = v.w;
        }
        {
            const int r  = t & 63;
            const int k0 = (t >> 6) * 16;
            const int gr = row0 + r;
            if (gr < N) {
#pragma unroll
                for (int kk = 0; kk < 16; kk += 4) {
                    float4 v = *(const float4*)(x + (size_t)gr * 64 + k0 + kk);
                    xsT[k0 + kk][r]     = v.x;
                    xsT[k0 + kk + 1][r] = v.y;
                    xsT[k0 + kk + 2][r] = v.z;
                    xsT[k0 + kk + 3][r] = v.w;
                }
            } else {
#pragma unroll
                for (int kk = 0; kk < 16; ++kk) xsT[k0 + kk][r] = 0.0f;
            }
        }
        __syncthreads();
        const int c4 = (t & 15) * 4;
        const int r4 = (t >> 4) * 4;
        float acc[4][4];
#pragma unroll
        for (int i = 0; i < 4; ++i)
#pragma unroll
            for (int j = 0; j < 4; ++j) acc[i][j] = 0.0f;
#pragma unroll 4
        for (int k = 0; k < 64; ++k) {
            float4 wv = *(const float4*)&ws[k][c4];
            float4 xv = *(const float4*)&xsT[k][r4];
            float xa[4] = {xv.x, xv.y, xv.z, xv.w};
            float wa[4] = {wv.x, wv.y, wv.z, wv.w};
#pragma unroll
            for (int i = 0; i < 4; ++i)
#pragma unroll
                for (int j = 0; j < 4; ++j) acc[i][j] += xa[i] * wa[j];
        }
#pragma unroll
        for (int i = 0; i < 4; ++i) {
            const int gr = row0 + r4 + i;
            if (gr < N) {
                unsigned short o[4];
#pragma unroll
                for (int j = 0; j < 4; ++j)
                    o[j] = __bfloat16_as_ushort(__float2bfloat16(acc[i][j]));
                *(ushort4*)((unsigned short*)h1 + (size_t)gr * 64 + c4) =
                    *(const ushort4*)o;
            }
        }
    } else {
        // ---- edge block: 1024 edges, 4 independent chains/thread ----
        const int base = (bid >> 1) * 1024 + threadIdx.x;
        int d[4], s[4];
        bool ok[4];
#pragma unroll
        for (int u = 0; u < 4; ++u) {
            int idx = base + u * 256;
            ok[u] = idx < E;
            d[u] = ok[u] ? dst[idx] : 0;
            s[u] = ok[u] ? src[idx] : 0;
        }
        int r[4];
#pragma unroll
        for (int u = 0; u < 4; ++u)
            r[u] = ok[u] ? atomicAdd(&cnt[d[u]], 1) : 64;
#pragma unroll
        for (int u = 0; u < 4; ++u)
            if (r[u] < 64) pedge[(d[u] << 6) + r[u]] = (unsigned)s[u];
    }
}

__device__ __forceinline__ void bf8_fma(float* acc, uint4 r, float w) {
    const unsigned u[4] = {r.x, r.y, r.z, r.w};
#pragma unroll
    for (int k = 0; k < 4; ++k) {
        acc[2 * k]     += __uint_as_float(u[k] << 16) * w;
        acc[2 * k + 1] += __uint_as_float(u[k] & 0xffff0000u) * w;
    }
}

__device__ __forceinline__ void bf8_acc(float* acc, uint4 r) {
    const unsigned u[4] = {r.x, r.y, r.z, r.w};
#pragma unroll
    for (int k = 0; k < 4; ++k) {
        acc[2 * k]     += __uint_as_float(u[k] << 16);
        acc[2 * k + 1] += __uint_as_float(u[k] & 0xffff0000u);
    }
}

// ---- layer-1 agg: wave/node, 8 slots x 8 lanes x 8 bf16 feats, unroll x2.
// h1 unscaled; per-edge weight ds = rsqrt(cnt[s]+1) from L2-resident cnt.
// out = relu(dn*(sum ds*h[s] + dn*h[n]) + b) -> bf16.
__global__ void agg1_kernel(const __hip_bfloat16* __restrict__ h,
                            const unsigned* __restrict__ pedge, const int* __restrict__ cnt,
                            const float* __restrict__ b, __hip_bfloat16* __restrict__ z) {
    const int n = (blockIdx.x * blockDim.x + threadIdx.x) >> 6;
    const int lane = threadIdx.x & 63;
    const int c = cnt[n];
    const int deg = (c < 64) ? c : 64;
    const int q  = lane >> 3;
    const int fq = (lane & 7) * 8;
    const int base = n << 6;
    const unsigned short* hp = (const unsigned short*)h;
    float acc[8];
#pragma unroll
    for (int i = 0; i < 8; ++i) acc[i] = 0.0f;
    for (int j = q; j < deg; j += 16) {
        int s0 = (int)pedge[base + j];
        float w0 = rsqrtf((float)cnt[s0] + 1.0f);
        uint4 r0 = *(const uint4*)(hp + (size_t)s0 * 64 + fq);
        int j2 = j + 8;
        if (j2 < deg) {
            int s1 = (int)pedge[base + j2];
            float w1 = rsqrtf((float)cnt[s1] + 1.0f);
            uint4 r1 = *(const uint4*)(hp + (size_t)s1 * 64 + fq);
            bf8_fma(acc, r0, w0);
            bf8_fma(acc, r1, w1);
        } else {
            bf8_fma(acc, r0, w0);
        }
    }
#pragma unroll
    for (int i = 0; i < 8; ++i) {
        acc[i] += __shfl_xor(acc[i], 8);
        acc[i] += __shfl_xor(acc[i], 16);
        acc[i] += __shfl_xor(acc[i], 32);
    }
    if (q == 0) {
        float dn = rsqrtf((float)c + 1.0f);
        uint4 sr = *(const uint4*)(hp + (size_t)n * 64 + fq);
        bf8_fma(acc, sr, dn);  // self term
        float4 b0 = *(const float4*)(b + fq);
        float4 b1 = *(const float4*)(b + fq + 4);
        float bb[8] = {b0.x, b0.y, b0.z, b0.w, b1.x, b1.y, b1.z, b1.w};
        unsigned short o[8];
#pragma unroll
        for (int i = 0; i < 8; ++i) {
            float v = fmaxf(dn * acc[i] + bb[i], 0.0f);
            o[i] = __bfloat16_as_ushort(__float2bfloat16(v));
        }
        *(uint4*)((unsigned short*)z + (size_t)n * 64 + fq) = *(const uint4*)o;
    }
}

// ---- gemm2: h2s[n] = (z1 @ W2)[n] * dis[n] -> bf16 (dis folded; cnt final) ----
__global__ void __launch_bounds__(256) gemm2_kernel(
    const __hip_bfloat16* __restrict__ Z, const float* __restrict__ W2,
    const int* __restrict__ cnt, __hip_bfloat16* __restrict__ H2) {
    __shared__ float ws[64][32];
    __shared__ float xs[32][64];
    const int t = threadIdx.x;
    for (int i = t; i < 64 * 32; i += 256) ws[i >> 5][i & 31] = W2[i];
    const int row0 = blockIdx.x * 32;
    const unsigned short* Zp = (const unsigned short*)Z;
#pragma unroll
    for (int h = 0; h < 2; ++h) {
        int idx = h * 1024 + t * 4;
        int r = idx >> 6, k = idx & 63;
        ushort4 v = *(const ushort4*)(Zp + (size_t)(row0 + r) * 64 + k);
        xs[r][k]     = __uint_as_float((unsigned)v.x << 16);
        xs[r][k + 1] = __uint_as_float((unsigned)v.y << 16);
        xs[r][k + 2] = __uint_as_float((unsigned)v.z << 16);
        xs[r][k + 3] = __uint_as_float((unsigned)v.w << 16);
    }
    __syncthreads();
    const int c  = t & 31;
    const int rb = (t >> 5) * 4;
    float acc[4] = {0.f, 0.f, 0.f, 0.f};
    for (int k0 = 0; k0 < 64; k0 += 4) {
        float w0 = ws[k0][c], w1 = ws[k0 + 1][c];
        float w2 = ws[k0 + 2][c], w3 = ws[k0 + 3][c];
#pragma unroll
        for (int i = 0; i < 4; ++i) {
            float4 xv = *(const float4*)&xs[rb + i][k0];
            acc[i] += xv.x * w0;
            acc[i] += xv.y * w1;
            acc[i] += xv.z * w2;
            acc[i] += xv.w * w3;
        }
    }
#pragma unroll
    for (int i = 0; i < 4; ++i) {
        int row = row0 + rb + i;
        float dn = rsqrtf((float)cnt[row] + 1.0f);
        H2[(size_t)row * 32 + c] = __float2bfloat16(acc[i] * dn);
    }
}

// ---- layer-2 agg: wave/node, 16 slots x 4 lanes x 8 bf16 feats, unroll x2.
// h2s pre-scaled by dis[src]. out = dn*(sum + h2s[n]) + b -> f32. ----
__global__ void agg2_kernel(const __hip_bfloat16* __restrict__ h,
                            const unsigned* __restrict__ pedge, const int* __restrict__ cnt,
                            const float* __restrict__ b, float* __restrict__ out) {
    const int n = (blockIdx.x * blockDim.x + threadIdx.x) >> 6;
    const int lane = threadIdx.x & 63;
    const int c = cnt[n];
    const int deg = (c < 64) ? c : 64;
    const int q  = lane >> 2;
    const int fq = (lane & 3) * 8;
    const int base = n << 6;
    const unsigned short* hp = (const unsigned short*)h;
    float acc[8];
#pragma unroll
    for (int i = 0; i < 8; ++i) acc[i] = 0.0f;
    for (int j = q; j < deg; j += 32) {
        int s0 = (int)pedge[base + j];
        uint4 r0 = *(const uint4*)(hp + (size_t)s0 * 32 + fq);
        int j2 = j + 16;
        if (j2 < deg) {
            int s1 = (int)pedge[base + j2];
            uint4 r1 = *(const uint4*)(hp + (size_t)s1 * 32 + fq);
            bf8_acc(acc, r0);
            bf8_acc(acc, r1);
        } else {
            bf8_acc(acc, r0);
        }
    }
#pragma unroll
    for (int i = 0; i < 8; ++i) {
        acc[i] += __shfl_xor(acc[i], 4);
        acc[i] += __shfl_xor(acc[i], 8);
        acc[i] += __shfl_xor(acc[i], 16);
        acc[i] += __shfl_xor(acc[i], 32);
    }
    if (q == 0) {
        float dn = rsqrtf((float)c + 1.0f);
        uint4 sr = *(const uint4*)(hp + (size_t)n * 32 + fq);
        bf8_acc(acc, sr);  // self term (h2s already has one dis factor)
        float4 b0 = *(const float4*)(b + fq);
        float4 b1 = *(const float4*)(b + fq + 4);
        float bb[8] = {b0.x, b0.y, b0.z, b0.w, b1.x, b1.y, b1.z, b1.w};
        float o[8];
#pragma unroll
        for (int i = 0; i < 8; ++i) o[i] = dn * acc[i] + bb[i];
        *(float4*)(out + (size_t)n * 32 + fq)     = make_float4(o[0], o[1], o[2], o[3]);
        *(float4*)(out + (size_t)n * 32 + fq + 4) = make_float4(o[4], o[5], o[6], o[7]);
    }
}

extern "C" void kernel_launch(void* const* d_in, const int* in_sizes, int n_in,
                              void* d_out, int out_size, void* d_ws, size_t ws_size,
                              hipStream_t stream) {
    const float* x  = (const float*)d_in[0];
    const int*   ei = (const int*)d_in[1];
    const float* W1 = (const float*)d_in[2];
    const float* b1 = (const float*)d_in[3];
    const float* W2 = (const float*)d_in[4];
    const float* b2 = (const float*)d_in[5];
    float* out = (float*)d_out;

    const int* src = ei;
    const int* dst = ei + E;

    constexpr size_t NP = 100352;
    int*      cnt   = (int*)d_ws;                              // NP ints
    unsigned* pedge = (unsigned*)(cnt + NP);                   // N*64 (25.6 MB)
    __hip_bfloat16* h1b = (__hip_bfloat16*)(pedge + (size_t)N * 64);  // N*64
    __hip_bfloat16* z1b = h1b + (size_t)N * 64;                       // N*64
    __hip_bfloat16* h2s = z1b + (size_t)N * 64;                       // N*32

    hipMemsetAsync(cnt, 0, NP * sizeof(int), stream);
    fused_gemm1_rank_kernel<<<GB + EBK, 256, 0, stream>>>(x, W1, h1b, src, dst,
                                                          cnt, pedge);
    agg1_kernel<<<N / 4, 256, 0, stream>>>(h1b, pedge, cnt, b1, z1b);
    gemm2_kernel<<<N / 32, 256, 0, stream>>>(z1b, W2, cnt, h2s);
    agg2_kernel<<<N / 4, 256, 0, stream>>>(h2s, pedge, cnt, b2, out);
}

// Round 13
// 225.728 us; speedup vs baseline: 1.2084x; 1.1445x over previous
//
#include <hip/hip_runtime.h>
#include <hip/hip_bf16.h>

// GCN 2-layer, N=100000, E=1.6M, 64->64(relu)->32.
// out[d] = dis[d]*(sum_{s in N(d)} dis[s]*h[s] + dis[d]*h[d]) + b  (per layer).
// Structure build in two phases to kill cross-XCD write amplification:
//  pass1: partition edges into 391 coarse dst-ranges (chunk-reserved appends,
//         ~150k atomics), fused with gemm1 (x@W1 -> h1 bf16, unscaled).
//  pass2: one block per range bins its 256 dsts via LDS cursors (no global
//         atomics; pedge lines single-writer; cnt written coalesced).
// agg1 applies dis[src] per edge from L2-resident cnt; gemm2 folds dis[n].

constexpr int N = 100000;
constexpr int E = 1600000;
constexpr int NBINS = 391;     // coarse ranges of 256 dsts
constexpr int CAP  = 5120;     // records per range (mean 4083, +16 sigma)
constexpr int P1B  = 391;      // pass1 blocks (4096 edges each)
constexpr int GB   = 1563;     // gemm1 blocks (64 rows each)

// ---- fused: pass1 partition (bid<P1B) | gemm1 outer-product (else) ----
__global__ void __launch_bounds__(256) fused_pass1_gemm1(
    const float* __restrict__ x, const float* __restrict__ W1,
    __hip_bfloat16* __restrict__ h1,
    const int* __restrict__ src, const int* __restrict__ dst,
    int* __restrict__ cursor, uint2* __restrict__ rec) {
    __shared__ float ws[64][64];    // 16 KB (pass1 reuses as int scratch)
    __shared__ float xsT[64][64];   // 16 KB
    const int bid = blockIdx.x;
    const int t = threadIdx.x;
    if (bid < P1B) {
        int* hist  = (int*)ws;          // NBINS+1
        int* rbase = hist + 392;        // NBINS+1
        int* rcur  = rbase + 392;       // NBINS+1
        for (int i = t; i < 392; i += 256) hist[i] = 0;
        __syncthreads();
        int myd[16], mys[16];
        const int e0 = bid * 4096;
#pragma unroll
        for (int it = 0; it < 16; ++it) {
            int idx = e0 + it * 256 + t;
            bool ok = idx < E;
            myd[it] = ok ? dst[idx] : -1;
            mys[it] = ok ? src[idx] : 0;
            if (ok) atomicAdd(&hist[myd[it] >> 8], 1);
        }
        __syncthreads();
        for (int i = t; i < 392; i += 256) {
            int h = hist[i];
            rbase[i] = (h > 0) ? atomicAdd(&cursor[i], h) : 0;
            rcur[i] = 0;
        }
        __syncthreads();
#pragma unroll
        for (int it = 0; it < 16; ++it) {
            if (myd[it] >= 0) {
                int cb = myd[it] >> 8;
                int r = atomicAdd(&rcur[cb], 1);
                int pos = rbase[cb] + r;
                if (pos < CAP)
                    rec[(size_t)cb * CAP + pos] =
                        make_uint2((unsigned)mys[it], (unsigned)myd[it]);
            }
        }
    } else {
        // ---- gemm block: 64 rows, outer-product 4x4 per thread ----
        const int row0 = (bid - P1B) * 64;
        for (int i = t * 4; i < 64 * 64; i += 1024) {
            float4 v = *(const float4*)(W1 + i);
            ws[i >> 6][i & 63]       = v.x;
            ws[i >> 6][(i & 63) + 1] = v.y;
            ws[i >> 6][(i & 63) + 2] = v.z;
            ws[i >> 6][(i & 63) + 3] = v.w;
        }
        {
            const int r  = t & 63;
            const int k0 = (t >> 6) * 16;
            const int gr = row0 + r;
            if (gr < N) {
#pragma unroll
                for (int kk = 0; kk < 16; kk += 4) {
                    float4 v = *(const float4*)(x + (size_t)gr * 64 + k0 + kk);
                    xsT[k0 + kk][r]     = v.x;
                    xsT[k0 + kk + 1][r] = v.y;
                    xsT[k0 + kk + 2][r] = v.z;
                    xsT[k0 + kk + 3][r] = v.w;
                }
            } else {
#pragma unroll
                for (int kk = 0; kk < 16; ++kk) xsT[k0 + kk][r] = 0.0f;
            }
        }
        __syncthreads();
        const int c4 = (t & 15) * 4;
        const int r4 = (t >> 4) * 4;
        float acc[4][4];
#pragma unroll
        for (int i = 0; i < 4; ++i)
#pragma unroll
            for (int j = 0; j < 4; ++j) acc[i][j] = 0.0f;
#pragma unroll 4
        for (int k = 0; k < 64; ++k) {
            float4 wv = *(const float4*)&ws[k][c4];
            float4 xv = *(const float4*)&xsT[k][r4];
            float xa[4] = {xv.x, xv.y, xv.z, xv.w};
            float wa[4] = {wv.x, wv.y, wv.z, wv.w};
#pragma unroll
            for (int i = 0; i < 4; ++i)
#pragma unroll
                for (int j = 0; j < 4; ++j) acc[i][j] += xa[i] * wa[j];
        }
#pragma unroll
        for (int i = 0; i < 4; ++i) {
            const int gr = row0 + r4 + i;
            if (gr < N) {
                unsigned short o[4];
#pragma unroll
                for (int j = 0; j < 4; ++j)
                    o[j] = __bfloat16_as_ushort(__float2bfloat16(acc[i][j]));
                *(ushort4*)((unsigned short*)h1 + (size_t)gr * 64 + c4) =
                    *(const ushort4*)o;
            }
        }
    }
}

// ---- pass2: bin one coarse range; single-writer buckets, no global atomics ----
__global__ void __launch_bounds__(256) pass2_kernel(
    const uint2* __restrict__ rec, const int* __restrict__ cursor,
    unsigned* __restrict__ pedge, int* __restrict__ cnt) {
    __shared__ int cur[256];
    const int cb = blockIdx.x;
    const int t = threadIdx.x;
    cur[t] = 0;
    __syncthreads();
    int m = cursor[cb];
    if (m > CAP) m = CAP;
    for (int i = t; i < m; i += 256) {
        uint2 u = rec[(size_t)cb * CAP + i];
        int d = (int)u.y, s = (int)u.x;
        int r = atomicAdd(&cur[d & 255], 1);
        if (r < 64) pedge[((size_t)d << 6) + r] = (unsigned)s;
    }
    __syncthreads();
    cnt[cb * 256 + t] = cur[t];
}

__device__ __forceinline__ void bf8_fma(float* acc, uint4 r, float w) {
    const unsigned u[4] = {r.x, r.y, r.z, r.w};
#pragma unroll
    for (int k = 0; k < 4; ++k) {
        acc[2 * k]     += __uint_as_float(u[k] << 16) * w;
        acc[2 * k + 1] += __uint_as_float(u[k] & 0xffff0000u) * w;
    }
}

__device__ __forceinline__ void bf8_acc(float* acc, uint4 r) {
    const unsigned u[4] = {r.x, r.y, r.z, r.w};
#pragma unroll
    for (int k = 0; k < 4; ++k) {
        acc[2 * k]     += __uint_as_float(u[k] << 16);
        acc[2 * k + 1] += __uint_as_float(u[k] & 0xffff0000u);
    }
}

// ---- layer-1 agg: wave/node, 8 slots x 8 lanes x 8 bf16 feats, unroll x2.
// h1 unscaled; per-edge weight ds = rsqrt(cnt[s]+1) from L2-resident cnt.
__global__ void agg1_kernel(const __hip_bfloat16* __restrict__ h,
                            const unsigned* __restrict__ pedge, const int* __restrict__ cnt,
                            const float* __restrict__ b, __hip_bfloat16* __restrict__ z) {
    const int n = (blockIdx.x * blockDim.x + threadIdx.x) >> 6;
    const int lane = threadIdx.x & 63;
    const int c = cnt[n];
    const int deg = (c < 64) ? c : 64;
    const int q  = lane >> 3;
    const int fq = (lane & 7) * 8;
    const size_t base = (size_t)n << 6;
    const unsigned short* hp = (const unsigned short*)h;
    float acc[8];
#pragma unroll
    for (int i = 0; i < 8; ++i) acc[i] = 0.0f;
    for (int j = q; j < deg; j += 16) {
        int s0 = (int)pedge[base + j];
        float w0 = rsqrtf((float)cnt[s0] + 1.0f);
        uint4 r0 = *(const uint4*)(hp + (size_t)s0 * 64 + fq);
        int j2 = j + 8;
        if (j2 < deg) {
            int s1 = (int)pedge[base + j2];
            float w1 = rsqrtf((float)cnt[s1] + 1.0f);
            uint4 r1 = *(const uint4*)(hp + (size_t)s1 * 64 + fq);
            bf8_fma(acc, r0, w0);
            bf8_fma(acc, r1, w1);
        } else {
            bf8_fma(acc, r0, w0);
        }
    }
#pragma unroll
    for (int i = 0; i < 8; ++i) {
        acc[i] += __shfl_xor(acc[i], 8);
        acc[i] += __shfl_xor(acc[i], 16);
        acc[i] += __shfl_xor(acc[i], 32);
    }
    if (q == 0) {
        float dn = rsqrtf((float)c + 1.0f);
        uint4 sr = *(const uint4*)(hp + (size_t)n * 64 + fq);
        bf8_fma(acc, sr, dn);  // self term
        float4 b0 = *(const float4*)(b + fq);
        float4 b1 = *(const float4*)(b + fq + 4);
        float bb[8] = {b0.x, b0.y, b0.z, b0.w, b1.x, b1.y, b1.z, b1.w};
        unsigned short o[8];
#pragma unroll
        for (int i = 0; i < 8; ++i) {
            float v = fmaxf(dn * acc[i] + bb[i], 0.0f);
            o[i] = __bfloat16_as_ushort(__float2bfloat16(v));
        }
        *(uint4*)((unsigned short*)z + (size_t)n * 64 + fq) = *(const uint4*)o;
    }
}

// ---- gemm2: h2s[n] = (z1 @ W2)[n] * dis[n] -> bf16 ----
__global__ void __launch_bounds__(256) gemm2_kernel(
    const __hip_bfloat16* __restrict__ Z, const float* __restrict__ W2,
    const int* __restrict__ cnt, __hip_bfloat16* __restrict__ H2) {
    __shared__ float ws[64][32];
    __shared__ float xs[32][64];
    const int t = threadIdx.x;
    for (int i = t; i < 64 * 32; i += 256) ws[i >> 5][i & 31] = W2[i];
    const int row0 = blockIdx.x * 32;
    const unsigned short* Zp = (const unsigned short*)Z;
#pragma unroll
    for (int h = 0; h < 2; ++h) {
        int idx = h * 1024 + t * 4;
        int r = idx >> 6, k = idx & 63;
        ushort4 v = *(const ushort4*)(Zp + (size_t)(row0 + r) * 64 + k);
        xs[r][k]     = __uint_as_float((unsigned)v.x << 16);
        xs[r][k + 1] = __uint_as_float((unsigned)v.y << 16);
        xs[r][k + 2] = __uint_as_float((unsigned)v.z << 16);
        xs[r][k + 3] = __uint_as_float((unsigned)v.w << 16);
    }
    __syncthreads();
    const int c  = t & 31;
    const int rb = (t >> 5) * 4;
    float acc[4] = {0.f, 0.f, 0.f, 0.f};
    for (int k0 = 0; k0 < 64; k0 += 4) {
        float w0 = ws[k0][c], w1 = ws[k0 + 1][c];
        float w2 = ws[k0 + 2][c], w3 = ws[k0 + 3][c];
#pragma unroll
        for (int i = 0; i < 4; ++i) {
            float4 xv = *(const float4*)&xs[rb + i][k0];
            acc[i] += xv.x * w0;
            acc[i] += xv.y * w1;
            acc[i] += xv.z * w2;
            acc[i] += xv.w * w3;
        }
    }
#pragma unroll
    for (int i = 0; i < 4; ++i) {
        int row = row0 + rb + i;
        float dn = rsqrtf((float)cnt[row] + 1.0f);
        H2[(size_t)row * 32 + c] = __float2bfloat16(acc[i] * dn);
    }
}

// ---- layer-2 agg: wave/node, 16 slots x 4 lanes x 8 bf16 feats, unroll x2 ----
__global__ void agg2_kernel(const __hip_bfloat16* __restrict__ h,
                            const unsigned* __restrict__ pedge, const int* __restrict__ cnt,
                            const float* __restrict__ b, float* __restrict__ out) {
    const int n = (blockIdx.x * blockDim.x + threadIdx.x) >> 6;
    const int lane = threadIdx.x & 63;
    const int c = cnt[n];
    const int deg = (c < 64) ? c : 64;
    const int q  = lane >> 2;
    const int fq = (lane & 3) * 8;
    const size_t base = (size_t)n << 6;
    const unsigned short* hp = (const unsigned short*)h;
    float acc[8];
#pragma unroll
    for (int i = 0; i < 8; ++i) acc[i] = 0.0f;
    for (int j = q; j < deg; j += 32) {
        int s0 = (int)pedge[base + j];
        uint4 r0 = *(const uint4*)(hp + (size_t)s0 * 32 + fq);
        int j2 = j + 16;
        if (j2 < deg) {
            int s1 = (int)pedge[base + j2];
            uint4 r1 = *(const uint4*)(hp + (size_t)s1 * 32 + fq);
            bf8_acc(acc, r0);
            bf8_acc(acc, r1);
        } else {
            bf8_acc(acc, r0);
        }
    }
#pragma unroll
    for (int i = 0; i < 8; ++i) {
        acc[i] += __shfl_xor(acc[i], 4);
        acc[i] += __shfl_xor(acc[i], 8);
        acc[i] += __shfl_xor(acc[i], 16);
        acc[i] += __shfl_xor(acc[i], 32);
    }
    if (q == 0) {
        float dn = rsqrtf((float)c + 1.0f);
        uint4 sr = *(const uint4*)(hp + (size_t)n * 32 + fq);
        bf8_acc(acc, sr);  // self term (h2s already has one dis factor)
        float4 b0 = *(const float4*)(b + fq);
        float4 b1 = *(const float4*)(b + fq + 4);
        float bb[8] = {b0.x, b0.y, b0.z, b0.w, b1.x, b1.y, b1.z, b1.w};
        float o[8];
#pragma unroll
        for (int i = 0; i < 8; ++i) o[i] = dn * acc[i] + bb[i];
        *(float4*)(out + (size_t)n * 32 + fq)     = make_float4(o[0], o[1], o[2], o[3]);
        *(float4*)(out + (size_t)n * 32 + fq + 4) = make_float4(o[4], o[5], o[6], o[7]);
    }
}

extern "C" void kernel_launch(void* const* d_in, const int* in_sizes, int n_in,
                              void* d_out, int out_size, void* d_ws, size_t ws_size,
                              hipStream_t stream) {
    const float* x  = (const float*)d_in[0];
    const int*   ei = (const int*)d_in[1];
    const float* W1 = (const float*)d_in[2];
    const float* b1 = (const float*)d_in[3];
    const float* W2 = (const float*)d_in[4];
    const float* b2 = (const float*)d_in[5];
    float* out = (float*)d_out;

    const int* src = ei;
    const int* dst = ei + E;

    constexpr size_t NP = 100352;
    int*      cursor = (int*)d_ws;                             // 512 ints
    int*      cnt    = cursor + 512;                           // NP ints
    unsigned* pedge  = (unsigned*)(cnt + NP);                  // N*64 (25.6 MB)
    uint2*    rec    = (uint2*)(pedge + (size_t)N * 64);       // NBINS*CAP (16 MB)
    __hip_bfloat16* h1b = (__hip_bfloat16*)(rec + (size_t)NBINS * CAP); // N*64
    __hip_bfloat16* z1b = h1b + (size_t)N * 64;                          // N*64
    __hip_bfloat16* h2s = z1b + (size_t)N * 64;                          // N*32

    hipMemsetAsync(cursor, 0, 512 * sizeof(int), stream);
    fused_pass1_gemm1<<<P1B + GB, 256, 0, stream>>>(x, W1, h1b, src, dst,
                                                    cursor, rec);
    pass2_kernel<<<NBINS, 256, 0, stream>>>(rec, cursor, pedge, cnt);
    agg1_kernel<<<N / 4, 256, 0, stream>>>(h1b, pedge, cnt, b1, z1b);
    gemm2_kernel<<<N / 32, 256, 0, stream>>>(z1b, W2, cnt, h2s);
    agg2_kernel<<<N / 4, 256, 0, stream>>>(h2s, pedge, cnt, b2, out);
}